// Round 1
// baseline (372.909 us; speedup 1.0000x reference)
//
#include <hip/hip_runtime.h>

// GCNConv: out[v] = isd[v] * sum_{(u->v)} x[u] * isd[u],  isd = rsqrt(max(outdeg,1))
// N=100000, E=1600000, D=128 fp32.
//
// R1 -> R2: bucketed gather killed the 800MB atomic write storm (866 -> 367us).
// R2 -> R3: dst-range slicing (blockIdx%8 heuristic) for bucket-store L2
//           locality (367 -> 343us). WRITE_SIZE stayed 134MB.
// R3 -> R4: the 134MB WRITE_SIZE is 3.2M device-scope atomics x ~32B each at
//           the memory-side coherence point (per-XCD L2s are non-coherent, so
//           agent atomics bypass L2). Fix: slice ownership = ACTUAL XCD id via
//           s_getreg(HW_REG_XCC_ID); then cnt/deg atomics are provably
//           XCD-exclusive and can use WORKGROUP scope -> executed in local TCC
//           (L2-resident RMW on ~100KB). Chunk work-stealing per XCD; a sweep
//           kernel with device-scope atomics covers any unclaimed chunks so
//           correctness never depends on the dispatcher's XCD coverage.

#define D_FEAT 128
#define CAP 32
#define NODES_PER_BLOCK 8   // gather: 256 threads, 32 lanes (float4) per node
#define NSLICES 8           // == number of XCDs on MI355X
#define CHUNK 4096          // edges per stolen chunk
#define BUILD_BLOCKS 2048
#define SWEEP_BLOCKS 64

__device__ __forceinline__ int xcc_id() {
    int x;
    asm("s_getreg_b32 %0, hwreg(HW_REG_XCC_ID)" : "=s"(x));
    return x & (NSLICES - 1);
}

__device__ __forceinline__ int atom_add_wg(int* p, int v) {
    // Executes in the local XCD's L2 (no sc1). Legal ONLY because each address
    // is touched by blocks of a single XCD (slice == physical XCC_ID).
    return __hip_atomic_fetch_add(p, v, __ATOMIC_RELAXED, __HIP_MEMORY_SCOPE_WORKGROUP);
}

__global__ void build_kernel(const int* __restrict__ src, const int* __restrict__ dst,
                             int* __restrict__ deg, int* __restrict__ cnt,
                             int* __restrict__ bucket, int2* __restrict__ ovf,
                             int* __restrict__ novf, int* __restrict__ chunkCtr,
                             int E, int sliceSz, int nChunks) {
    int slice = xcc_id();                 // ownership = physical XCD
    int lo = slice * sliceSz;
    int hi = lo + sliceSz;
    __shared__ int sh_chunk;

    for (;;) {
        __syncthreads();
        if (threadIdx.x == 0)
            sh_chunk = atom_add_wg(&chunkCtr[slice], 1);  // XCD-local counter
        __syncthreads();
        int c = sh_chunk;
        if (c >= nChunks) return;

        int beg = c * CHUNK;
        int end = min(E, beg + CHUNK);
        for (int i = beg + (int)threadIdx.x; i < end; i += blockDim.x) {
            int s = src[i];
            int d = dst[i];
            if (d >= lo && d < hi) {                      // this XCD owns dst-range
                int slot = atom_add_wg(&cnt[d], 1);       // L2-local RMW
                if (slot < CAP) {
                    bucket[d * CAP + slot] = s;           // L2-local store (1.6MB slice)
                } else {
                    int o = atomicAdd(novf, 1);           // global list: device scope
                    ovf[o] = make_int2(s, d);
                }
            }
            if (s >= lo && s < hi) {                      // out-degree histogram
                atom_add_wg(&deg[s], 1);                  // L2-local RMW
            }
        }
    }
}

// Safety net: dispatch->XCD coverage is formally undefined. Any chunks a slice's
// XCD never claimed are processed here with DEVICE-scope atomics (correct across
// XCDs; build's L2 state was flushed at kernel end). Normal case: 64 atomic
// reads past nChunks, immediate exit (~2us).
__global__ void sweep_kernel(const int* __restrict__ src, const int* __restrict__ dst,
                             int* __restrict__ deg, int* __restrict__ cnt,
                             int* __restrict__ bucket, int2* __restrict__ ovf,
                             int* __restrict__ novf, int* __restrict__ chunkCtr,
                             int E, int sliceSz, int nChunks) {
    int slice = blockIdx.x & (NSLICES - 1);
    int lo = slice * sliceSz;
    int hi = lo + sliceSz;
    __shared__ int sh_chunk;

    for (;;) {
        __syncthreads();
        if (threadIdx.x == 0)
            sh_chunk = atomicAdd(&chunkCtr[slice], 1);    // device scope
        __syncthreads();
        int c = sh_chunk;
        if (c >= nChunks) return;

        int beg = c * CHUNK;
        int end = min(E, beg + CHUNK);
        for (int i = beg + (int)threadIdx.x; i < end; i += blockDim.x) {
            int s = src[i];
            int d = dst[i];
            if (d >= lo && d < hi) {
                int slot = atomicAdd(&cnt[d], 1);
                if (slot < CAP) {
                    bucket[d * CAP + slot] = s;
                } else {
                    int o = atomicAdd(novf, 1);
                    ovf[o] = make_int2(s, d);
                }
            }
            if (s >= lo && s < hi) {
                atomicAdd(&deg[s], 1);
            }
        }
    }
}

__global__ void isd_kernel(const int* __restrict__ deg, float* __restrict__ isd, int N) {
    int i = blockIdx.x * blockDim.x + threadIdx.x;
    if (i < N) isd[i] = rsqrtf(fmaxf((float)deg[i], 1.0f));
}

// 8 nodes per 256-thread block; 32 threads per node, float4 per thread.
__global__ void gather_kernel(const float4* __restrict__ x4,
                              const int* __restrict__ cnt,
                              const int* __restrict__ bucket,
                              const float* __restrict__ isd,
                              float4* __restrict__ out4, int N) {
    __shared__ int   sh_idx[NODES_PER_BLOCK * CAP];
    __shared__ float sh_w[NODES_PER_BLOCK * CAP];
    int t = threadIdx.x;
    int node_slot = t >> 5;
    int lane = t & 31;
    int d = blockIdx.x * NODES_PER_BLOCK + node_slot;

    int c = 0;
    if (d < N) {
        c = min(cnt[d], CAP);
        if (lane < c) {
            int s = bucket[d * CAP + lane];
            sh_idx[node_slot * CAP + lane] = s;
            sh_w[node_slot * CAP + lane] = isd[s];
        }
    }
    __syncthreads();
    if (d >= N) return;

    float4 acc = {0.f, 0.f, 0.f, 0.f};
    #pragma unroll 4
    for (int k = 0; k < c; ++k) {
        int s   = sh_idx[node_slot * CAP + k];   // broadcast LDS read
        float w = sh_w[node_slot * CAP + k];
        float4 v = x4[s * 32 + lane];            // 512B coalesced row gather
        acc.x += v.x * w; acc.y += v.y * w;
        acc.z += v.z * w; acc.w += v.w * w;
    }
    float wd = isd[d];
    acc.x *= wd; acc.y *= wd; acc.z *= wd; acc.w *= wd;
    out4[d * 32 + lane] = acc;                   // single non-atomic row write
}

__global__ void overflow_kernel(const float* __restrict__ x,
                                const float* __restrict__ isd,
                                const int2* __restrict__ ovf,
                                const int* __restrict__ novf,
                                float* __restrict__ out) {
    int n = *novf;
    for (int e = blockIdx.x; e < n; e += gridDim.x) {
        int2 sd = ovf[e];
        float coef = isd[sd.x] * isd[sd.y];
        atomicAdd(&out[sd.y * D_FEAT + threadIdx.x],
                  x[sd.x * D_FEAT + threadIdx.x] * coef);
    }
}

// ---- fallback (ws too small): round-1 atomic scatter ----
__global__ void fb_degree_kernel(const int* __restrict__ src,
                                 float* __restrict__ deg, int E) {
    int i = blockIdx.x * blockDim.x + threadIdx.x;
    if (i < E) atomicAdd(&deg[src[i]], 1.0f);
}
__global__ void fb_inv_sqrt_kernel(float* __restrict__ deg, int N) {
    int i = blockIdx.x * blockDim.x + threadIdx.x;
    if (i < N) deg[i] = rsqrtf(fmaxf(deg[i], 1.0f));
}
__global__ void fb_scatter_kernel(const float* __restrict__ x,
                                  const int* __restrict__ src,
                                  const int* __restrict__ dst,
                                  const float* __restrict__ isd,
                                  float* __restrict__ out, int E) {
    int e = blockIdx.x;
    if (e >= E) return;
    int f = threadIdx.x;
    int s = src[e], d = dst[e];
    float coef = isd[s] * isd[d];
    atomicAdd(&out[(long)d * D_FEAT + f], x[(long)s * D_FEAT + f] * coef);
}

extern "C" void kernel_launch(void* const* d_in, const int* in_sizes, int n_in,
                              void* d_out, int out_size, void* d_ws, size_t ws_size,
                              hipStream_t stream) {
    const float* x   = (const float*)d_in[0];
    const int*   src = (const int*)d_in[1];
    const int*   dst = (const int*)d_in[2];
    float* out = (float*)d_out;

    int N = in_sizes[0] / D_FEAT;   // 100000
    int E = in_sizes[1];            // 1600000

    size_t off_deg    = 0;
    size_t off_cnt    = off_deg + (size_t)N * 4;
    size_t off_misc   = off_cnt + (size_t)N * 4;   // novf @+0, chunkCtr[8] @+16
    size_t off_isd    = off_misc + 64;
    size_t off_bucket = off_isd + (size_t)N * 4;
    size_t off_ovf    = off_bucket + (size_t)N * CAP * 4;
    size_t needed     = off_ovf + (size_t)E * 8;

    if (ws_size < needed) {
        float* deg = (float*)d_ws;
        hipMemsetAsync(deg, 0, (size_t)N * sizeof(float), stream);
        hipMemsetAsync(out, 0, (size_t)out_size * sizeof(float), stream);
        fb_degree_kernel<<<(E + 255) / 256, 256, 0, stream>>>(src, deg, E);
        fb_inv_sqrt_kernel<<<(N + 255) / 256, 256, 0, stream>>>(deg, N);
        fb_scatter_kernel<<<E, D_FEAT, 0, stream>>>(x, src, dst, deg, out, E);
        return;
    }

    char* ws = (char*)d_ws;
    int*   deg      = (int*)(ws + off_deg);
    int*   cnt      = (int*)(ws + off_cnt);
    int*   novf     = (int*)(ws + off_misc);
    int*   chunkCtr = (int*)(ws + off_misc + 16);
    float* isd      = (float*)(ws + off_isd);
    int*   bucket   = (int*)(ws + off_bucket);
    int2*  ovf      = (int2*)(ws + off_ovf);

    hipMemsetAsync(ws, 0, off_isd, stream);  // deg, cnt, novf, chunkCtr

    int sliceSz = (N + NSLICES - 1) / NSLICES;
    int nChunks = (E + CHUNK - 1) / CHUNK;

    build_kernel<<<BUILD_BLOCKS, 256, 0, stream>>>(src, dst, deg, cnt, bucket,
                                                   ovf, novf, chunkCtr,
                                                   E, sliceSz, nChunks);
    sweep_kernel<<<SWEEP_BLOCKS, 256, 0, stream>>>(src, dst, deg, cnt, bucket,
                                                   ovf, novf, chunkCtr,
                                                   E, sliceSz, nChunks);
    isd_kernel<<<(N + 255) / 256, 256, 0, stream>>>(deg, isd, N);
    gather_kernel<<<(N + NODES_PER_BLOCK - 1) / NODES_PER_BLOCK, 256, 0, stream>>>(
        (const float4*)x, cnt, bucket, isd, (float4*)out, N);
    overflow_kernel<<<64, D_FEAT, 0, stream>>>(x, isd, ovf, novf, out);
}